// Round 8
// baseline (151.099 us; speedup 1.0000x reference)
//
#include <hip/hip_runtime.h>
#include <math.h>

#define NT  512   // fft kernel: threads per block; one block per channel h
#define NTC 256   // cauchy kernel block size (grid (H,4), 8 blocks/CU, 8 waves/SIMD)

// Packed f32 pair. All hot complex math is explicit VOP3P (v_pk_*_f32) inline
// asm with op_sel/neg modifiers (convention HW-validated R6/R7).
typedef float v2 __attribute__((ext_vector_type(2)));

__device__ __forceinline__ v2 vrot(v2 a){ return (v2){-a.y, a.x}; }            // i*a
__device__ __forceinline__ v2 vconj(v2 a){ return (v2){a.x, -a.y}; }

// a + i*b : (a.x - b.y, a.y + b.x) -- one v_pk_add_f32
__device__ __forceinline__ v2 pk_addrot(v2 a, v2 b){
    v2 d;
    asm("v_pk_add_f32 %0, %1, %2 op_sel:[0,1] op_sel_hi:[1,0] neg_lo:[0,1] neg_hi:[0,0]"
        : "=v"(d) : "v"(a), "v"(b));
    return d;
}
// a - i*b : (a.x + b.y, a.y - b.x)
__device__ __forceinline__ v2 pk_subrot(v2 a, v2 b){
    v2 d;
    asm("v_pk_add_f32 %0, %1, %2 op_sel:[0,1] op_sel_hi:[1,0] neg_lo:[0,0] neg_hi:[0,1]"
        : "=v"(d) : "v"(a), "v"(b));
    return d;
}
// complex a*b
__device__ __forceinline__ v2 vcmul(v2 a, v2 b){
    v2 d;
    asm("v_pk_mul_f32 %0, %1, %2 op_sel:[0,0] op_sel_hi:[0,1]"
        : "=v"(d) : "v"(a), "v"(b));
    asm("v_pk_fma_f32 %0, %1, %2, %0 op_sel:[1,1,0] op_sel_hi:[1,0,1] neg_lo:[0,1,0] neg_hi:[0,0,0]"
        : "+v"(d) : "v"(a), "v"(b));
    return d;
}
// complex a*conj(b)
__device__ __forceinline__ v2 vcmulc(v2 a, v2 b){
    v2 d;
    asm("v_pk_mul_f32 %0, %1, %2 op_sel:[0,0] op_sel_hi:[0,1] neg_lo:[0,0] neg_hi:[0,1]"
        : "=v"(d) : "v"(a), "v"(b));
    asm("v_pk_fma_f32 %0, %1, %2, %0 op_sel:[1,1,0] op_sel_hi:[1,0,1]"
        : "+v"(d) : "v"(a), "v"(b));
    return d;
}

// ---- P1 packed-denominator helpers (pair over two i-lanes) ----
__device__ __forceinline__ v2 pk_add_bh(v2 a, v2 s){
    v2 d;
    asm("v_pk_add_f32 %0, %1, %2 op_sel:[0,1] op_sel_hi:[1,1]"
        : "=v"(d) : "v"(a), "s"(s));
    return d;
}
__device__ __forceinline__ v2 pk_fma_sq_bh(v2 a, v2 s){
    v2 d;
    asm("v_pk_fma_f32 %0, %1, %1, %2 op_sel:[0,0,1] op_sel_hi:[1,1,1]"
        : "=v"(d) : "v"(a), "s"(s));
    return d;
}
__device__ __forceinline__ v2 pk_mul_cross(v2 a){
    v2 d;
    asm("v_pk_mul_f32 %0, %1, %1 op_sel:[1,0] op_sel_hi:[0,1]"
        : "=v"(d) : "v"(a));
    return d;
}
__device__ __forceinline__ v2 pk_inv_lo(v2 rr, v2 dd){
    v2 d;
    asm("v_pk_mul_f32 %0, %1, %2 op_sel:[0,1] op_sel_hi:[0,0]"
        : "=v"(d) : "v"(rr), "v"(dd));
    return d;
}
__device__ __forceinline__ v2 pk_inv_hi(v2 rr, v2 dd){
    v2 d;
    asm("v_pk_mul_f32 %0, %1, %2 op_sel:[1,1] op_sel_hi:[1,0]"
        : "=v"(d) : "v"(rr), "v"(dd));
    return d;
}
__device__ __forceinline__ v2 pk_mul_bl(v2 a, v2 s){
    v2 d;
    asm("v_pk_mul_f32 %0, %1, %2 op_sel:[0,0] op_sel_hi:[1,0]"
        : "=v"(d) : "v"(a), "s"(s));
    return d;
}
__device__ __forceinline__ v2 pk_mulp(v2 a, v2 b){
    v2 d;
    asm("v_pk_mul_f32 %0, %1, %2 op_sel:[0,0] op_sel_hi:[1,1]"
        : "=v"(d) : "v"(a), "v"(b));
    return d;
}
__device__ __forceinline__ void fmaBlo(v2& acc, v2 w, v2 p){
    asm("v_pk_fma_f32 %0, %1, %2, %0 op_sel:[0,0,0] op_sel_hi:[0,1,1]"
        : "+v"(acc) : "s"(w), "v"(p));
}
__device__ __forceinline__ void fmaBhi(v2& acc, v2 w, v2 p){
    asm("v_pk_fma_f32 %0, %1, %2, %0 op_sel:[1,0,0] op_sel_hi:[1,1,1]"
        : "+v"(acc) : "s"(w), "v"(p));
}
__device__ __forceinline__ void fmaBlon(v2& acc, v2 w, v2 p){
    asm("v_pk_fma_f32 %0, %1, %2, %0 op_sel:[0,0,0] op_sel_hi:[0,1,1] neg_lo:[1,0,0] neg_hi:[1,0,0]"
        : "+v"(acc) : "s"(w), "v"(p));
}

// XOR bank swizzle
__device__ __forceinline__ int SW(int e){ return e ^ (((e>>5) ^ (e>>9)) & 15); }
__device__ __forceinline__ v2& q512(v2* buf, int tbs, int k){
    return *(v2*)((char*)buf + ((tbs ^ (k<<3)) + (k<<12)));
}
__device__ __forceinline__ v2& q512u(v2* buf, int tbs, int k){
    return *(v2*)((char*)buf + (((tbs ^ 64) ^ (k<<3)) + (k<<12) + 32768));
}
__device__ __forceinline__ int d8r4(int x){
    return ((x&7)<<9) | (((x>>3)&7)<<6) | (((x>>6)&7)<<3) | ((x>>9)&7);
}
__device__ __forceinline__ int rev3(int t){
    return ((t&7)<<6) | (t&56) | ((t>>6)&7);
}

__device__ __forceinline__ void load_row(const v2* twd, int rowIdx, v2 W[7]) {
    const float4* rp4 = (const float4*)(twd + rowIdx*8);
    float4 q0 = rp4[0], q1 = rp4[1], q2 = rp4[2], q3 = rp4[3];
    W[0]=(v2){q0.x,q0.y}; W[1]=(v2){q0.z,q0.w}; W[2]=(v2){q1.x,q1.y};
    W[3]=(v2){q1.z,q1.w}; W[4]=(v2){q2.x,q2.y}; W[5]=(v2){q2.z,q2.w};
    W[6]=(v2){q3.x,q3.y};
}

__device__ __forceinline__ void dft8_inv(v2 t[8], v2 y[8]) {
    const float RH = 0.70710678f;
    v2 p  = t[0]+t[4], m  = t[0]-t[4], q  = t[2]+t[6], r  = t[2]-t[6];
    v2 E0 = p+q, E2 = p-q;
    v2 E1 = pk_addrot(m, r), E3 = pk_subrot(m, r);
    v2 p2 = t[1]+t[5], m2 = t[1]-t[5], q2 = t[3]+t[7], r2 = t[3]-t[7];
    v2 O0 = p2+q2, O2 = p2-q2;
    v2 O1 = pk_addrot(m2, r2), O3 = pk_subrot(m2, r2);
    v2 W1O = RH * pk_addrot(O1, O1);
    v2 A3  = RH * pk_addrot(O3, O3);
    y[0] = E0 + O0;  y[4] = E0 - O0;
    y[1] = E1 + W1O; y[5] = E1 - W1O;
    y[2] = pk_addrot(E2, O2); y[6] = pk_subrot(E2, O2);
    y[3] = pk_addrot(E3, A3); y[7] = pk_subrot(E3, A3);
}

__device__ __forceinline__ void dft8_inv_lo4(v2 t[8], v2 y[4]) {
    const float RH = 0.70710678f;
    v2 p  = t[0]+t[4], m  = t[0]-t[4], q  = t[2]+t[6], r  = t[2]-t[6];
    v2 E0 = p+q, E2 = p-q;
    v2 E1 = pk_addrot(m, r), E3 = pk_subrot(m, r);
    v2 p2 = t[1]+t[5], m2 = t[1]-t[5], q2 = t[3]+t[7], r2 = t[3]-t[7];
    v2 O0 = p2+q2, O2 = p2-q2;
    v2 O1 = pk_addrot(m2, r2), O3 = pk_subrot(m2, r2);
    v2 W1O = RH * pk_addrot(O1, O1);
    v2 A3  = RH * pk_addrot(O3, O3);
    y[0] = E0 + O0;
    y[1] = E1 + W1O;
    y[2] = pk_addrot(E2, O2);
    y[3] = pk_addrot(E3, A3);
}

__device__ __forceinline__ void dft8_fwd(v2 t[8], v2 y[8]) {
    const float RH = 0.70710678f;
    v2 p  = t[0]+t[4], m  = t[0]-t[4], q  = t[2]+t[6], r  = t[2]-t[6];
    v2 E0 = p+q, E2 = p-q;
    v2 E1 = pk_subrot(m, r), E3 = pk_addrot(m, r);
    v2 p2 = t[1]+t[5], m2 = t[1]-t[5], q2 = t[3]+t[7], r2 = t[3]-t[7];
    v2 O0 = p2+q2, O2 = p2-q2;
    v2 O1 = pk_subrot(m2, r2), O3 = pk_addrot(m2, r2);
    v2 W1O = RH * pk_subrot(O1, O1);
    v2 A3f = RH * pk_addrot(O3, O3);
    y[0] = E0 + O0;  y[4] = E0 - O0;
    y[1] = E1 + W1O; y[5] = E1 - W1O;
    y[2] = pk_subrot(E2, O2); y[6] = pk_addrot(E2, O2);
    y[3] = E3 - A3f; y[7] = E3 + A3f;
}

template<int Q, bool BAR>
__device__ __forceinline__ void r8_dit_inv(v2* buf, int tid, const v2* twd) {
    int j = tid & (Q-1);
    v2 W[7];
    load_row(twd, (512/Q)*j, W);
    int base = 8*tid - 7*j;
    v2 t[8];
    #pragma unroll
    for (int k = 0; k < 8; ++k) t[k] = buf[SW(base + k*Q)];
    #pragma unroll
    for (int k = 0; k < 7; ++k) t[k+1] = vcmul(t[k+1], W[k]);
    v2 y[8];
    dft8_inv(t, y);
    #pragma unroll
    for (int m = 0; m < 8; ++m) buf[SW(base + m*Q)] = y[m];
    if (BAR) __syncthreads();
    else     __builtin_amdgcn_wave_barrier();
}

template<int Q, bool BAR>
__device__ __forceinline__ void r8_dif_fwd(v2* buf, int tid, const v2* twd) {
    if (Q == 1) {
        const int b0  = tid << 6;
        const int bt  = tid << 3;
        const int mLs = (((bt>>5) ^ (bt>>9)) & 15) << 3;
        const int msU = (mLs ^ 64) + 32768;
        #pragma unroll 1
        for (int hh = 0; hh < 2; ++hh) {
            const int ms = hh ? msU : mLs;
            v2 t[8];
            #pragma unroll
            for (int k = 0; k < 8; ++k)
                t[k] = *(v2*)((char*)buf + ((b0 + (k<<3)) ^ ms));
            v2 y[8];
            dft8_fwd(t, y);
            #pragma unroll
            for (int m = 0; m < 8; ++m)
                *(v2*)((char*)buf + ((b0 + (m<<3)) ^ ms)) = y[m];
        }
        if (BAR) __syncthreads();
        else     __builtin_amdgcn_wave_barrier();
        return;
    }
    int j = tid & (Q-1);
    int baseL = 8*tid - 7*j;
    v2 W[7];
    load_row(twd, (512/Q)*j, W);
    #pragma unroll 1
    for (int hh = 0; hh < 2; ++hh) {
        int base = baseL + (hh << 12);
        v2 t[8];
        #pragma unroll
        for (int k = 0; k < 8; ++k) t[k] = buf[SW(base + k*Q)];
        v2 y[8];
        dft8_fwd(t, y);
        #pragma unroll
        for (int k = 0; k < 7; ++k) y[k+1] = vcmulc(y[k+1], W[k]);
        #pragma unroll
        for (int m = 0; m < 8; ++m) buf[SW(base + m*Q)] = y[m];
    }
    if (BAR) __syncthreads();
    else     __builtin_amdgcn_wave_barrier();
}

// ---- prep kernel: blocks 0..H-1 per-(h,n) weights; block H: twiddle table;
//      block H+1: tan table (only if full); block H+2: W_8192 row (if full).
__global__ void __launch_bounds__(64)
s4_prep(const float* __restrict__ Lre, const float* __restrict__ Lim,
        const float* __restrict__ Pre, const float* __restrict__ Pim,
        const float* __restrict__ Bre, const float* __restrict__ Bim,
        const float* __restrict__ Cin,
        float* __restrict__ ws8, float* __restrict__ ws1,
        v2* __restrict__ twd, float* __restrict__ tanv,
        v2* __restrict__ w8192, int full)
{
    int b = blockIdx.x;
    int nb = (int)gridDim.x;
    if (b == nb - 3) {
        const float fm = 6.2831853072f / 4096.0f;
        #pragma unroll
        for (int r = 0; r < 8; ++r) {
            int j = r*64 + (int)threadIdx.x;
            #pragma unroll
            for (int k = 0; k < 7; ++k) {
                float s, c; __sincosf(fm * (float)(j*(k+1)), &s, &c);
                twd[j*8 + k] = (v2){c, s};
            }
            twd[j*8 + 7] = (v2){1.0f, 0.0f};
        }
        return;
    }
    if (b == nb - 2) {
        if (!full) return;
        // tanv[l] = -sin(0.5*ang)/cos(0.5*ang), ang = -2pi l/4096 (matches P1's form)
        #pragma unroll 1
        for (int r = 0; r < 64; ++r) {
            int l = r*64 + (int)threadIdx.x;
            float ang = -6.2831855f * ((float)l * (1.0f/4096.0f));
            float sh, ch; __sincosf(0.5f*ang, &sh, &ch);
            tanv[l] = -sh * __builtin_amdgcn_rcpf(ch);
        }
        return;
    }
    if (b == nb - 1) {
        if (!full) return;
        const float fm2 = 6.2831853072f / 8192.0f;
        #pragma unroll
        for (int r = 0; r < 8; ++r) {
            int j = r*64 + (int)threadIdx.x;
            float s, c; __sincosf(fm2 * (float)j, &s, &c);
            w8192[j] = (v2){c, s};
        }
        return;
    }
    int idx = b*64 + threadIdx.x;   // h*64 + n
    float lre = fminf(Lre[idx], -1e-4f);
    float lim = Lim[idx];
    float pr = Pre[idx], pi = Pim[idx];
    float br = Bre[idx], bi = Bim[idx];
    float cr = Cin[2*idx], ci = Cin[2*idx+1];
    v2 cc = (v2){cr, -ci};
    v2 w00 = vcmul(cc, (v2){br, bi});
    v2 w01 = vcmul(cc, (v2){pr, pi});
    v2 w10 = vcmul((v2){pr,-pi}, (v2){br, bi});
    float* o = ws8 + idx*8;
    o[0] = -lre;  o[1] = -lim;
    o[2] = w00.x; o[3] = w00.y;
    o[4] = w01.x; o[5] = w01.y;
    o[6] = w10.x; o[7] = w10.y;
    ws1[2*idx]   = pr*pr + pi*pi;
    ws1[2*idx+1] = lre*lre;
}

// ---- Cauchy kernel: LDS-free, 8 waves/SIMD (256 thr x (H,4) grid = 8 blk/CU).
// Each thread: 4 l-values (l = qi*1024 + i*256 + tid), full 64-n contraction,
// writes atRoots to global (L2-resident; block->XCD mapping aligned with fft).
__global__ __attribute__((amdgpu_waves_per_eu(8, 8))) void __launch_bounds__(NTC)
s4_cauchy(const float* __restrict__ logstep,
          const float* __restrict__ ws8, const float* __restrict__ ws1,
          const float* __restrict__ tanv, v2* __restrict__ atR)
{
    const int tid = threadIdx.x;
    const int h   = blockIdx.x;
    const int qi  = blockIdx.y;
    const int lbase = qi*1024;

    const float step = expf(logstep[h]);
    const float tos  = 2.0f / step;
    const float hstep = 0.5f * step;
    const float4* pp4 = (const float4*)(ws8 + (h*64)*8);
    const v2* pw2 = (const v2*)(ws1 + h*128);

    v2 tvA, tvB;
    {
        float tv[4];
        #pragma unroll
        for (int i = 0; i < 4; ++i) {
            float tr = tos * tanv[lbase + (i<<8) + tid];
            tv[i] = fminf(fmaxf(tr, -1e12f), 1e12f);
        }
        tvA = (v2){tv[0], tv[1]};
        tvB = (v2){tv[2], tv[3]};
    }
    v2 aX00A=(v2)(0.f), aY00A=(v2)(0.f), aX00B=(v2)(0.f), aY00B=(v2)(0.f);
    v2 aX01A=(v2)(0.f), aY01A=(v2)(0.f), aX01B=(v2)(0.f), aY01B=(v2)(0.f);
    v2 aX10A=(v2)(0.f), aY10A=(v2)(0.f), aX10B=(v2)(0.f), aY10B=(v2)(0.f);
    v2 aX11A=(v2)(0.f), aY11A=(v2)(0.f), aX11B=(v2)(0.f), aY11B=(v2)(0.f);
    #pragma unroll 2
    for (int n = 0; n < 64; ++n) {
        float4 A = pp4[2*n], Bq = pp4[2*n+1];
        v2 lam = (v2){A.x, A.y};
        v2 w00 = (v2){A.z, A.w};
        v2 w01 = (v2){Bq.x, Bq.y};
        v2 w10 = (v2){Bq.z, Bq.w};
        v2 Wv  = pw2[n];
        v2 sA = pk_add_bh(tvA, lam), sB = pk_add_bh(tvB, lam);
        v2 dA = pk_fma_sq_bh(sA, Wv), dB = pk_fma_sq_bh(sB, Wv);
        v2 PA = pk_mul_cross(dA), PB = pk_mul_cross(dB);
        v2 RR;
        RR.x = __builtin_amdgcn_rcpf(PA.x);
        RR.y = __builtin_amdgcn_rcpf(PB.x);
        v2 invA = pk_inv_lo(RR, dA), invB = pk_inv_hi(RR, dB);
        v2 pxA = pk_mul_bl(invA, lam), pxB = pk_mul_bl(invB, lam);
        v2 pyA = pk_mulp(invA, sA),    pyB = pk_mulp(invB, sB);
        fmaBlo(aX00A, w00, pxA); fmaBhi(aX00A, w00, pyA);
        fmaBhi(aY00A, w00, pxA); fmaBlon(aY00A, w00, pyA);
        fmaBlo(aX00B, w00, pxB); fmaBhi(aX00B, w00, pyB);
        fmaBhi(aY00B, w00, pxB); fmaBlon(aY00B, w00, pyB);
        fmaBlo(aX01A, w01, pxA); fmaBhi(aX01A, w01, pyA);
        fmaBhi(aY01A, w01, pxA); fmaBlon(aY01A, w01, pyA);
        fmaBlo(aX01B, w01, pxB); fmaBhi(aX01B, w01, pyB);
        fmaBhi(aY01B, w01, pxB); fmaBlon(aY01B, w01, pyB);
        fmaBlo(aX10A, w10, pxA); fmaBhi(aX10A, w10, pyA);
        fmaBhi(aY10A, w10, pxA); fmaBlon(aY10A, w10, pyA);
        fmaBlo(aX10B, w10, pxB); fmaBhi(aX10B, w10, pyB);
        fmaBhi(aY10B, w10, pxB); fmaBlon(aY10B, w10, pyB);
        fmaBlo(aX11A, Wv, pxA);  fmaBlon(aY11A, Wv, pyA);
        fmaBlo(aX11B, Wv, pxB);  fmaBlon(aY11B, Wv, pyB);
    }
    float tvv[4] = { tvA.x, tvA.y, tvB.x, tvB.y };
    v2 k00[4] = { {aX00A.x,aY00A.x}, {aX00A.y,aY00A.y},
                  {aX00B.x,aY00B.x}, {aX00B.y,aY00B.y} };
    v2 k01[4] = { {aX01A.x,aY01A.x}, {aX01A.y,aY01A.y},
                  {aX01B.x,aY01B.x}, {aX01B.y,aY01B.y} };
    v2 k10[4] = { {aX10A.x,aY10A.x}, {aX10A.y,aY10A.y},
                  {aX10B.x,aY10B.x}, {aX10B.y,aY10B.y} };
    v2 k11[4] = { {aX11A.x,aY11A.x}, {aX11A.y,aY11A.y},
                  {aX11B.x,aY11B.x}, {aX11B.y,aY11B.y} };
    v2* aRo = atR + (size_t)h*4096 + lbase;
    #pragma unroll
    for (int i = 0; i < 4; ++i) {
        v2 opk = (v2){1.0f + k11[i].x, k11[i].y};
        float iv = __builtin_amdgcn_rcpf(opk.x*opk.x + opk.y*opk.y);
        v2 r11 = vconj(opk) * iv;
        v2 t  = vcmul(vcmul(k01[i], r11), k10[i]);
        v2 cf = (v2){1.0f, tvv[i]*hstep};
        aRo[(i<<8) + tid] = vcmul(cf, k00[i] - t);
    }
}

// ---- FFT kernel: the fused kernel minus P1. Q1 butterfly reads atRoots
// straight from global (coalesced, no LDS staging); P3/P5 use the W_8192 table.
__global__ __attribute__((amdgpu_waves_per_eu(4, 4))) void __launch_bounds__(NT)
s4_fft(const float* __restrict__ u, const float* __restrict__ Din,
       const v2* __restrict__ twd, const v2* __restrict__ w8192,
       const v2* __restrict__ atR, float* __restrict__ out)
{
    __shared__ v2 buf[8192];   // 64 KB -> 2 blocks/CU
    const int tid = threadIdx.x;
    const int h = blockIdx.x;
    const int tbs = (tid ^ ((tid>>5) & 15)) << 3;

    {   // P2 Q=1 butterfly: inputs straight from global atRoots
        const v2* aR = atR + (size_t)h*4096;
        v2 t[8];
        #pragma unroll
        for (int k = 0; k < 8; ++k) t[k] = aR[tid + 512*k];
        v2 y[8];
        dft8_inv(t, y);
        const int tb8 = 8*rev3(tid);
        const int b8  = tb8 << 3;
        const int m8s = (((tb8>>5) ^ (tb8>>9)) & 15) << 3;
        #pragma unroll
        for (int m = 0; m < 8; ++m)
            *(v2*)((char*)buf + ((b8 + (m<<3)) ^ m8s)) = y[m];
    }
    __syncthreads();

    // ---- P2: ifft4096 middle passes ----
    r8_dit_inv<8,  false>(buf, tid, twd);
    r8_dit_inv<64, true >(buf, tid, twd);

    // ---- P3: fused P2-Q512 (DIT) + pack z = u + i*K + r2 stage + DIF-Q512. ----
    {
        v2 W[7];
        load_row(twd, tid, W);
        v2 t[8];
        #pragma unroll
        for (int k = 0; k < 8; ++k) t[k] = q512(buf, tbs, k);
        #pragma unroll
        for (int k = 0; k < 7; ++k) t[k+1] = vcmul(t[k+1], W[k]);
        v2 y[8];
        dft8_inv(t, y);
        float uval[8];
        const float* up = u + h*4096;
        #pragma unroll
        for (int m = 0; m < 8; ++m) uval[m] = up[tid + 512*m];
        v2 cur0 = vconj(w8192[tid]);             // W_8192^{-tid}
        const v2 C16n = (v2){0.92387953f, -0.38268343f};
        v2 zL[8], zU[8];
        {
            v2 cur = cur0;
            #pragma unroll
            for (int k = 0; k < 8; ++k) {
                zL[k] = (v2){uval[k], y[k].x * (1.0f/4096.0f)};
                zU[k] = vcmul(zL[k], cur);
                cur = vcmul(cur, C16n);
            }
        }
        v2 s[8];
        dft8_fwd(zL, s);
        #pragma unroll
        for (int m = 1; m < 8; ++m) s[m] = vcmulc(s[m], W[m-1]);
        #pragma unroll
        for (int m = 0; m < 8; ++m) q512(buf, tbs, m) = s[m];
        dft8_fwd(zU, s);
        #pragma unroll
        for (int m = 1; m < 8; ++m) s[m] = vcmulc(s[m], W[m-1]);
        #pragma unroll
        for (int m = 0; m < 8; ++m) q512u(buf, tbs, m) = s[m];
    }
    __syncthreads();

    // ---- P4: forward fft8192 remaining stages ----
    r8_dif_fwd<64, false>(buf, tid, twd);
    r8_dif_fwd<8,  false>(buf, tid, twd);
    r8_dif_fwd<1,  true >(buf, tid, twd);

    // ---- P5: unpack + multiply + half-size-inverse pack + P6 Q=1 butterfly ----
    {
        v2 cur = w8192[tid];                     // W_8192^{+tid}
        const v2 C16p = (v2){0.92387953f, 0.38268343f};
        v2 v[8];
        #pragma unroll 1
        for (int i = 0; i < 8; ++i) {
            int r  = i*NT + tid;
            int par = (r&1)<<12;
            int e1 = par + d8r4(r>>1);
            int e3 = e1 + 4;
            int k2c = 4096 - r;
            int e4 = ((k2c&1)<<12) + d8r4((k2c>>1)&4095);
            int e2 = (r == 0) ? 0 : (e4 + 4);
            v2 za = buf[SW(e1)];
            v2 zb = buf[SW(e2)];
            v2 zc = buf[SW(e3)];
            v2 zd = buf[SW(e4)];
            v2 U1 = 0.5f*(za + vconj(zb));
            v2 K1 = -0.5f*vrot(za - vconj(zb));
            v2 Yr = vcmul(U1, K1);
            v2 U2 = 0.5f*(zc + vconj(zd));
            v2 K2 = -0.5f*vrot(zc - vconj(zd));
            v2 Ys = vcmul(U2, K2);
            v[i] = pk_addrot(Yr + Ys, vcmul(cur, Yr - Ys));
            cur = vcmul(cur, C16p);
        }
        __syncthreads();
        v2 y[8];
        dft8_inv(v, y);
        const int tb8 = 8*rev3(tid);
        const int b8  = tb8 << 3;
        const int m8s = (((tb8>>5) ^ (tb8>>9)) & 15) << 3;
        #pragma unroll
        for (int m = 0; m < 8; ++m)
            *(v2*)((char*)buf + ((b8 + (m<<3)) ^ m8s)) = y[m];
    }
    __syncthreads();

    // ---- P6: ifft4096 middle passes ----
    r8_dit_inv<8,  false>(buf, tid, twd);
    r8_dit_inv<64, true >(buf, tid, twd);

    // ---- P7: fused P6-Q512 butterfly + epilogue ----
    {
        v2 W[7];
        load_row(twd, tid, W);
        v2 t[8];
        #pragma unroll
        for (int k = 0; k < 8; ++k) t[k] = q512(buf, tbs, k);
        #pragma unroll
        for (int k = 0; k < 7; ++k) t[k+1] = vcmul(t[k+1], W[k]);
        v2 y[4];
        dft8_inv_lo4(t, y);
        const float Dh = Din[h];
        const float sc = 1.0f / 8192.0f;
        const v2* u2 = (const v2*)(u + h*4096);
        v2*     out2 = (v2*)(out + h*4096);
        #pragma unroll
        for (int m = 0; m < 4; ++m) {
            int n = tid + 512*m;
            out2[n] = sc*y[m] + Dh*u2[n];
        }
    }
}

// ---- fallback: R7 fused kernel, used if the workspace can't hold atRoots ----
__global__ __attribute__((amdgpu_waves_per_eu(4, 4))) void __launch_bounds__(NT)
s4_fused(const float* __restrict__ u,
         const float* __restrict__ Din, const float* __restrict__ logstep,
         const float* __restrict__ ws8, const float* __restrict__ ws1,
         const v2* __restrict__ twd,
         float* __restrict__ out)
{
    __shared__ v2 buf[8192];
    const int tid = threadIdx.x;
    const int h = blockIdx.x;
    const int tbs = (tid ^ ((tid>>5) & 15)) << 3;

    const float step = expf(logstep[h]);
    const float tos  = 2.0f / step;
    const float hstep = 0.5f * step;
    const float* pp = ws8 + (h*64)*8;
    const float4* pp4 = (const float4*)pp;
    const v2* pw2 = (const v2*)(ws1 + h*128);

    v2 a4[4];
    #pragma unroll 1
    for (int hp = 0; hp < 2; ++hp) {
        v2 tvA, tvB;
        {
            float tv[4];
            #pragma unroll
            for (int i = 0; i < 4; ++i) {
                int l = hp*(4*NT) + i*NT + tid;
                float ang = -6.2831855f * ((float)l * (1.0f/4096.0f));
                float sh, ch; __sincosf(0.5f*ang, &sh, &ch);
                float traw = -tos * sh * __builtin_amdgcn_rcpf(ch);
                tv[i] = fminf(fmaxf(traw, -1e12f), 1e12f);
            }
            tvA = (v2){tv[0], tv[1]};
            tvB = (v2){tv[2], tv[3]};
        }
        v2 aX00A=(v2)(0.f), aY00A=(v2)(0.f), aX00B=(v2)(0.f), aY00B=(v2)(0.f);
        v2 aX01A=(v2)(0.f), aY01A=(v2)(0.f), aX01B=(v2)(0.f), aY01B=(v2)(0.f);
        v2 aX10A=(v2)(0.f), aY10A=(v2)(0.f), aX10B=(v2)(0.f), aY10B=(v2)(0.f);
        v2 aX11A=(v2)(0.f), aY11A=(v2)(0.f), aX11B=(v2)(0.f), aY11B=(v2)(0.f);
        #pragma unroll 2
        for (int n = 0; n < 64; ++n) {
            float4 A = pp4[2*n], Bq = pp4[2*n+1];
            v2 lam = (v2){A.x, A.y};
            v2 w00 = (v2){A.z, A.w};
            v2 w01 = (v2){Bq.x, Bq.y};
            v2 w10 = (v2){Bq.z, Bq.w};
            v2 Wv  = pw2[n];
            v2 sA = pk_add_bh(tvA, lam), sB = pk_add_bh(tvB, lam);
            v2 dA = pk_fma_sq_bh(sA, Wv), dB = pk_fma_sq_bh(sB, Wv);
            v2 PA = pk_mul_cross(dA), PB = pk_mul_cross(dB);
            v2 RR;
            RR.x = __builtin_amdgcn_rcpf(PA.x);
            RR.y = __builtin_amdgcn_rcpf(PB.x);
            v2 invA = pk_inv_lo(RR, dA), invB = pk_inv_hi(RR, dB);
            v2 pxA = pk_mul_bl(invA, lam), pxB = pk_mul_bl(invB, lam);
            v2 pyA = pk_mulp(invA, sA),    pyB = pk_mulp(invB, sB);
            fmaBlo(aX00A, w00, pxA); fmaBhi(aX00A, w00, pyA);
            fmaBhi(aY00A, w00, pxA); fmaBlon(aY00A, w00, pyA);
            fmaBlo(aX00B, w00, pxB); fmaBhi(aX00B, w00, pyB);
            fmaBhi(aY00B, w00, pxB); fmaBlon(aY00B, w00, pyB);
            fmaBlo(aX01A, w01, pxA); fmaBhi(aX01A, w01, pyA);
            fmaBhi(aY01A, w01, pxA); fmaBlon(aY01A, w01, pyA);
            fmaBlo(aX01B, w01, pxB); fmaBhi(aX01B, w01, pyB);
            fmaBhi(aY01B, w01, pxB); fmaBlon(aY01B, w01, pyB);
            fmaBlo(aX10A, w10, pxA); fmaBhi(aX10A, w10, pyA);
            fmaBhi(aY10A, w10, pxA); fmaBlon(aY10A, w10, pyA);
            fmaBlo(aX10B, w10, pxB); fmaBhi(aX10B, w10, pyB);
            fmaBhi(aY10B, w10, pxB); fmaBlon(aY10B, w10, pyB);
            fmaBlo(aX11A, Wv, pxA);  fmaBlon(aY11A, Wv, pyA);
            fmaBlo(aX11B, Wv, pxB);  fmaBlon(aY11B, Wv, pyB);
        }
        float tvv[4] = { tvA.x, tvA.y, tvB.x, tvB.y };
        v2 k00[4] = { {aX00A.x,aY00A.x}, {aX00A.y,aY00A.y},
                      {aX00B.x,aY00B.x}, {aX00B.y,aY00B.y} };
        v2 k01[4] = { {aX01A.x,aY01A.x}, {aX01A.y,aY01A.y},
                      {aX01B.x,aY01B.x}, {aX01B.y,aY01B.y} };
        v2 k10[4] = { {aX10A.x,aY10A.x}, {aX10A.y,aY10A.y},
                      {aX10B.x,aY10B.x}, {aX10B.y,aY10B.y} };
        v2 k11[4] = { {aX11A.x,aY11A.x}, {aX11A.y,aY11A.y},
                      {aX11B.x,aY11B.x}, {aX11B.y,aY11B.y} };
        #pragma unroll
        for (int i = 0; i < 4; ++i) {
            v2 opk = (v2){1.0f + k11[i].x, k11[i].y};
            float iv = __builtin_amdgcn_rcpf(opk.x*opk.x + opk.y*opk.y);
            v2 r11 = vconj(opk) * iv;
            v2 t  = vcmul(vcmul(k01[i], r11), k10[i]);
            v2 cf = (v2){1.0f, tvv[i]*hstep};
            v2 res = vcmul(cf, k00[i] - t);
            if (hp == 0) q512(buf, tbs, i) = res;
            else         a4[i] = res;
        }
    }
    {
        v2 t[8];
        #pragma unroll
        for (int k = 0; k < 4; ++k) t[k] = q512(buf, tbs, k);
        #pragma unroll
        for (int k = 0; k < 4; ++k) t[4+k] = a4[k];
        __syncthreads();
        v2 y[8];
        dft8_inv(t, y);
        const int tb8 = 8*rev3(tid);
        const int b8  = tb8 << 3;
        const int m8s = (((tb8>>5) ^ (tb8>>9)) & 15) << 3;
        #pragma unroll
        for (int m = 0; m < 8; ++m)
            *(v2*)((char*)buf + ((b8 + (m<<3)) ^ m8s)) = y[m];
    }
    __syncthreads();

    r8_dit_inv<8,  false>(buf, tid, twd);
    r8_dit_inv<64, true >(buf, tid, twd);

    {
        v2 W[7];
        load_row(twd, tid, W);
        v2 t[8];
        #pragma unroll
        for (int k = 0; k < 8; ++k) t[k] = q512(buf, tbs, k);
        #pragma unroll
        for (int k = 0; k < 7; ++k) t[k+1] = vcmul(t[k+1], W[k]);
        v2 y[8];
        dft8_inv(t, y);
        float uval[8];
        const float* up = u + h*4096;
        #pragma unroll
        for (int m = 0; m < 8; ++m) uval[m] = up[tid + 512*m];
        float s2, c2; __sincosf(-6.2831853072f/8192.0f*(float)tid, &s2, &c2);
        v2 cur0 = (v2){c2, s2};
        const v2 C16n = (v2){0.92387953f, -0.38268343f};
        v2 zL[8], zU[8];
        {
            v2 cur = cur0;
            #pragma unroll
            for (int k = 0; k < 8; ++k) {
                zL[k] = (v2){uval[k], y[k].x * (1.0f/4096.0f)};
                zU[k] = vcmul(zL[k], cur);
                cur = vcmul(cur, C16n);
            }
        }
        v2 s[8];
        dft8_fwd(zL, s);
        #pragma unroll
        for (int m = 1; m < 8; ++m) s[m] = vcmulc(s[m], W[m-1]);
        #pragma unroll
        for (int m = 0; m < 8; ++m) q512(buf, tbs, m) = s[m];
        dft8_fwd(zU, s);
        #pragma unroll
        for (int m = 1; m < 8; ++m) s[m] = vcmulc(s[m], W[m-1]);
        #pragma unroll
        for (int m = 0; m < 8; ++m) q512u(buf, tbs, m) = s[m];
    }
    __syncthreads();

    r8_dif_fwd<64, false>(buf, tid, twd);
    r8_dif_fwd<8,  false>(buf, tid, twd);
    r8_dif_fwd<1,  true >(buf, tid, twd);

    {
        float sb, cb; __sincosf(6.2831853072f/8192.0f*(float)tid, &sb, &cb);
        v2 cur = (v2){cb, sb};
        const v2 C16p = (v2){0.92387953f, 0.38268343f};
        v2 v[8];
        #pragma unroll 1
        for (int i = 0; i < 8; ++i) {
            int r  = i*NT + tid;
            int par = (r&1)<<12;
            int e1 = par + d8r4(r>>1);
            int e3 = e1 + 4;
            int k2c = 4096 - r;
            int e4 = ((k2c&1)<<12) + d8r4((k2c>>1)&4095);
            int e2 = (r == 0) ? 0 : (e4 + 4);
            v2 za = buf[SW(e1)];
            v2 zb = buf[SW(e2)];
            v2 zc = buf[SW(e3)];
            v2 zd = buf[SW(e4)];
            v2 U1 = 0.5f*(za + vconj(zb));
            v2 K1 = -0.5f*vrot(za - vconj(zb));
            v2 Yr = vcmul(U1, K1);
            v2 U2 = 0.5f*(zc + vconj(zd));
            v2 K2 = -0.5f*vrot(zc - vconj(zd));
            v2 Ys = vcmul(U2, K2);
            v[i] = pk_addrot(Yr + Ys, vcmul(cur, Yr - Ys));
            cur = vcmul(cur, C16p);
        }
        __syncthreads();
        v2 y[8];
        dft8_inv(v, y);
        const int tb8 = 8*rev3(tid);
        const int b8  = tb8 << 3;
        const int m8s = (((tb8>>5) ^ (tb8>>9)) & 15) << 3;
        #pragma unroll
        for (int m = 0; m < 8; ++m)
            *(v2*)((char*)buf + ((b8 + (m<<3)) ^ m8s)) = y[m];
    }
    __syncthreads();

    r8_dit_inv<8,  false>(buf, tid, twd);
    r8_dit_inv<64, true >(buf, tid, twd);

    {
        v2 W[7];
        load_row(twd, tid, W);
        v2 t[8];
        #pragma unroll
        for (int k = 0; k < 8; ++k) t[k] = q512(buf, tbs, k);
        #pragma unroll
        for (int k = 0; k < 7; ++k) t[k+1] = vcmul(t[k+1], W[k]);
        v2 y[4];
        dft8_inv_lo4(t, y);
        const float Dh = Din[h];
        const float sc = 1.0f / 8192.0f;
        const v2* u2 = (const v2*)(u + h*4096);
        v2*     out2 = (v2*)(out + h*4096);
        #pragma unroll
        for (int m = 0; m < 4; ++m) {
            int n = tid + 512*m;
            out2[n] = sc*y[m] + Dh*u2[n];
        }
    }
}

extern "C" void kernel_launch(void* const* d_in, const int* in_sizes, int n_in,
                              void* d_out, int out_size, void* d_ws, size_t ws_size,
                              hipStream_t stream)
{
    const float* u       = (const float*)d_in[0];
    const float* Lre     = (const float*)d_in[1];
    const float* Lim     = (const float*)d_in[2];
    const float* Pre     = (const float*)d_in[3];
    const float* Pim     = (const float*)d_in[4];
    const float* Bre     = (const float*)d_in[5];
    const float* Bim     = (const float*)d_in[6];
    const float* Cin     = (const float*)d_in[7];
    const float* Din     = (const float*)d_in[8];
    const float* logstep = (const float*)d_in[9];
    float* out = (float*)d_out;
    const int H = in_sizes[8];  // D is [H,1]

    float* ws8   = (float*)d_ws;                       // H*64*8 floats (1 MB)
    float* ws1   = ws8 + (size_t)H*64*8;               // H*128 floats (256 KB)
    v2*    twd   = (v2*)(ws1 + (size_t)H*128);         // 512 rows x 8 v2 (32 KB)
    float* tanv  = (float*)(twd + 512*8);              // 4096 floats (16 KB)
    v2*    w8192 = (v2*)(tanv + 4096);                 // 512 v2 (4 KB)
    v2*    atR   = w8192 + 512;                        // H*4096 v2 (16 MB)
    size_t need_full = (size_t)((char*)(atR + (size_t)H*4096) - (char*)d_ws);
    int full = (ws_size >= need_full) ? 1 : 0;

    hipLaunchKernelGGL(s4_prep, dim3(H + 3), dim3(64), 0, stream,
                       Lre, Lim, Pre, Pim, Bre, Bim, Cin, ws8, ws1, twd,
                       tanv, w8192, full);
    if (full) {
        hipLaunchKernelGGL(s4_cauchy, dim3(H, 4), dim3(NTC), 0, stream,
                           logstep, ws8, ws1, tanv, atR);
        hipLaunchKernelGGL(s4_fft, dim3(H), dim3(NT), 0, stream,
                           u, Din, twd, w8192, atR, out);
    } else {
        hipLaunchKernelGGL(s4_fused, dim3(H), dim3(NT), 0, stream,
                           u, Din, logstep, ws8, ws1, twd, out);
    }
}

// Round 9
// 142.070 us; speedup vs baseline: 1.0636x; 1.0636x over previous
//
#include <hip/hip_runtime.h>
#include <math.h>

#define NT 512   // threads per block; 512 blocks (one per channel h)

// Packed f32 pair. All hot complex math is explicit VOP3P (v_pk_*_f32) inline
// asm with op_sel/neg modifiers. Convention (HW-validated R6/R7):
// op_sel[i] picks src i's word for the LOW result half, op_sel_hi[i] for the
// HIGH half (0=lo word, 1=hi word); neg_lo/neg_hi negate that source in the
// low/high result lane.
typedef float v2 __attribute__((ext_vector_type(2)));

__device__ __forceinline__ v2 vrot(v2 a){ return (v2){-a.y, a.x}; }            // i*a
__device__ __forceinline__ v2 vconj(v2 a){ return (v2){a.x, -a.y}; }

// a + i*b : (a.x - b.y, a.y + b.x) -- one v_pk_add_f32
__device__ __forceinline__ v2 pk_addrot(v2 a, v2 b){
    v2 d;
    asm("v_pk_add_f32 %0, %1, %2 op_sel:[0,1] op_sel_hi:[1,0] neg_lo:[0,1] neg_hi:[0,0]"
        : "=v"(d) : "v"(a), "v"(b));
    return d;
}
// a - i*b : (a.x + b.y, a.y - b.x)
__device__ __forceinline__ v2 pk_subrot(v2 a, v2 b){
    v2 d;
    asm("v_pk_add_f32 %0, %1, %2 op_sel:[0,1] op_sel_hi:[1,0] neg_lo:[0,0] neg_hi:[0,1]"
        : "=v"(d) : "v"(a), "v"(b));
    return d;
}
// a + conj(b) : (a.x + b.x, a.y - b.y)
__device__ __forceinline__ v2 pk_addc(v2 a, v2 b){
    v2 d;
    asm("v_pk_add_f32 %0, %1, %2 op_sel:[0,0] op_sel_hi:[1,1] neg_hi:[0,1]"
        : "=v"(d) : "v"(a), "v"(b));
    return d;
}
// a - conj(b) : (a.x - b.x, a.y + b.y)
__device__ __forceinline__ v2 pk_subc(v2 a, v2 b){
    v2 d;
    asm("v_pk_add_f32 %0, %1, %2 op_sel:[0,0] op_sel_hi:[1,1] neg_lo:[0,1]"
        : "=v"(d) : "v"(a), "v"(b));
    return d;
}
// 0.5 * t  (inline const broadcast)
__device__ __forceinline__ v2 pk_half(v2 t){
    v2 d;
    asm("v_pk_mul_f32 %0, %1, 0.5 op_sel:[0,0] op_sel_hi:[1,0]"
        : "=v"(d) : "v"(t));
    return d;
}
// -0.5 * i * t : (0.5*t.y, -0.5*t.x)
__device__ __forceinline__ v2 pk_nih(v2 t){
    v2 d;
    asm("v_pk_mul_f32 %0, %1, 0.5 op_sel:[1,0] op_sel_hi:[0,0] neg_hi:[1,0]"
        : "=v"(d) : "v"(t));
    return d;
}
// complex a*b
__device__ __forceinline__ v2 vcmul(v2 a, v2 b){
    v2 d;
    asm("v_pk_mul_f32 %0, %1, %2 op_sel:[0,0] op_sel_hi:[0,1]"
        : "=v"(d) : "v"(a), "v"(b));
    asm("v_pk_fma_f32 %0, %1, %2, %0 op_sel:[1,1,0] op_sel_hi:[1,0,1] neg_lo:[0,1,0] neg_hi:[0,0,0]"
        : "+v"(d) : "v"(a), "v"(b));
    return d;
}
// complex a*conj(b)
__device__ __forceinline__ v2 vcmulc(v2 a, v2 b){
    v2 d;
    asm("v_pk_mul_f32 %0, %1, %2 op_sel:[0,0] op_sel_hi:[0,1] neg_lo:[0,0] neg_hi:[0,1]"
        : "=v"(d) : "v"(a), "v"(b));
    asm("v_pk_fma_f32 %0, %1, %2, %0 op_sel:[1,1,0] op_sel_hi:[1,0,1]"
        : "+v"(d) : "v"(a), "v"(b));
    return d;
}

// ---- P1 packed-denominator helpers (pair over two i-lanes) ----
__device__ __forceinline__ v2 pk_add_bh(v2 a, v2 s){
    v2 d;
    asm("v_pk_add_f32 %0, %1, %2 op_sel:[0,1] op_sel_hi:[1,1]"
        : "=v"(d) : "v"(a), "s"(s));
    return d;
}
__device__ __forceinline__ v2 pk_fma_sq_bh(v2 a, v2 s){
    v2 d;
    asm("v_pk_fma_f32 %0, %1, %1, %2 op_sel:[0,0,1] op_sel_hi:[1,1,1]"
        : "=v"(d) : "v"(a), "s"(s));
    return d;
}
__device__ __forceinline__ v2 pk_mul_cross(v2 a){
    v2 d;
    asm("v_pk_mul_f32 %0, %1, %1 op_sel:[1,0] op_sel_hi:[0,1]"
        : "=v"(d) : "v"(a));
    return d;
}
__device__ __forceinline__ v2 pk_inv_lo(v2 rr, v2 dd){
    v2 d;
    asm("v_pk_mul_f32 %0, %1, %2 op_sel:[0,1] op_sel_hi:[0,0]"
        : "=v"(d) : "v"(rr), "v"(dd));
    return d;
}
__device__ __forceinline__ v2 pk_inv_hi(v2 rr, v2 dd){
    v2 d;
    asm("v_pk_mul_f32 %0, %1, %2 op_sel:[1,1] op_sel_hi:[1,0]"
        : "=v"(d) : "v"(rr), "v"(dd));
    return d;
}
__device__ __forceinline__ v2 pk_mul_bl(v2 a, v2 s){
    v2 d;
    asm("v_pk_mul_f32 %0, %1, %2 op_sel:[0,0] op_sel_hi:[1,0]"
        : "=v"(d) : "v"(a), "s"(s));
    return d;
}
__device__ __forceinline__ v2 pk_mulp(v2 a, v2 b){
    v2 d;
    asm("v_pk_mul_f32 %0, %1, %2 op_sel:[0,0] op_sel_hi:[1,1]"
        : "=v"(d) : "v"(a), "v"(b));
    return d;
}
__device__ __forceinline__ void fmaBlo(v2& acc, v2 w, v2 p){
    asm("v_pk_fma_f32 %0, %1, %2, %0 op_sel:[0,0,0] op_sel_hi:[0,1,1]"
        : "+v"(acc) : "s"(w), "v"(p));
}
__device__ __forceinline__ void fmaBhi(v2& acc, v2 w, v2 p){
    asm("v_pk_fma_f32 %0, %1, %2, %0 op_sel:[1,0,0] op_sel_hi:[1,1,1]"
        : "+v"(acc) : "s"(w), "v"(p));
}
__device__ __forceinline__ void fmaBlon(v2& acc, v2 w, v2 p){
    asm("v_pk_fma_f32 %0, %1, %2, %0 op_sel:[0,0,0] op_sel_hi:[0,1,1] neg_lo:[1,0,0] neg_hi:[1,0,0]"
        : "+v"(acc) : "s"(w), "v"(p));
}

// XOR bank swizzle
__device__ __forceinline__ int SW(int e){ return e ^ (((e>>5) ^ (e>>9)) & 15); }

// ---- cheap-address forms of SW for the structured access patterns ----
//   SW(tid+512k) = (tid ^ ((tid>>5)&15) ^ k) + 512k
__device__ __forceinline__ v2& q512(v2* buf, int tbs, int k){
    return *(v2*)((char*)buf + ((tbs ^ (k<<3)) + (k<<12)));
}
__device__ __forceinline__ v2& q512u(v2* buf, int tbs, int k){
    return *(v2*)((char*)buf + (((tbs ^ 64) ^ (k<<3)) + (k<<12) + 32768));
}

// base-8 digit reversal of a 12-bit index
__device__ __forceinline__ int d8r4(int x){
    return ((x&7)<<9) | (((x>>3)&7)<<6) | (((x>>6)&7)<<3) | ((x>>9)&7);
}
// base-8 digit reversal of a 9-bit index (thread id <-> butterfly block)
__device__ __forceinline__ int rev3(int t){
    return ((t&7)<<6) | (t&56) | ((t>>6)&7);
}

// ---- load one 7-twiddle row (padded to 8 v2 = 64B) from the global table.
__device__ __forceinline__ void load_row(const v2* twd, int rowIdx, v2 W[7]) {
    const float4* rp4 = (const float4*)(twd + rowIdx*8);
    float4 q0 = rp4[0], q1 = rp4[1], q2 = rp4[2], q3 = rp4[3];
    W[0]=(v2){q0.x,q0.y}; W[1]=(v2){q0.z,q0.w}; W[2]=(v2){q1.x,q1.y};
    W[3]=(v2){q1.z,q1.w}; W[4]=(v2){q2.x,q2.y}; W[5]=(v2){q2.z,q2.w};
    W[6]=(v2){q3.x,q3.y};
}

// ---- 8-point DFT, inverse sign (sigma=+1). y_m = sum_k t_k w^{mk}, w=e^{+i pi/4}
__device__ __forceinline__ void dft8_inv(v2 t[8], v2 y[8]) {
    const float RH = 0.70710678f;
    v2 p  = t[0]+t[4], m  = t[0]-t[4], q  = t[2]+t[6], r  = t[2]-t[6];
    v2 E0 = p+q, E2 = p-q;
    v2 E1 = pk_addrot(m, r), E3 = pk_subrot(m, r);
    v2 p2 = t[1]+t[5], m2 = t[1]-t[5], q2 = t[3]+t[7], r2 = t[3]-t[7];
    v2 O0 = p2+q2, O2 = p2-q2;
    v2 O1 = pk_addrot(m2, r2), O3 = pk_subrot(m2, r2);
    v2 W1O = RH * pk_addrot(O1, O1);
    v2 A3  = RH * pk_addrot(O3, O3);
    y[0] = E0 + O0;  y[4] = E0 - O0;
    y[1] = E1 + W1O; y[5] = E1 - W1O;
    y[2] = pk_addrot(E2, O2); y[6] = pk_subrot(E2, O2);
    y[3] = pk_addrot(E3, A3); y[7] = pk_subrot(E3, A3);
}

// ---- pruned: only y[0..3] (P7 epilogue discards the mirror half).
__device__ __forceinline__ void dft8_inv_lo4(v2 t[8], v2 y[4]) {
    const float RH = 0.70710678f;
    v2 p  = t[0]+t[4], m  = t[0]-t[4], q  = t[2]+t[6], r  = t[2]-t[6];
    v2 E0 = p+q, E2 = p-q;
    v2 E1 = pk_addrot(m, r), E3 = pk_subrot(m, r);
    v2 p2 = t[1]+t[5], m2 = t[1]-t[5], q2 = t[3]+t[7], r2 = t[3]-t[7];
    v2 O0 = p2+q2, O2 = p2-q2;
    v2 O1 = pk_addrot(m2, r2), O3 = pk_subrot(m2, r2);
    v2 W1O = RH * pk_addrot(O1, O1);
    v2 A3  = RH * pk_addrot(O3, O3);
    y[0] = E0 + O0;
    y[1] = E1 + W1O;
    y[2] = pk_addrot(E2, O2);
    y[3] = pk_addrot(E3, A3);
}

// ---- 8-point DFT, forward sign (sigma=-1).
__device__ __forceinline__ void dft8_fwd(v2 t[8], v2 y[8]) {
    const float RH = 0.70710678f;
    v2 p  = t[0]+t[4], m  = t[0]-t[4], q  = t[2]+t[6], r  = t[2]-t[6];
    v2 E0 = p+q, E2 = p-q;
    v2 E1 = pk_subrot(m, r), E3 = pk_addrot(m, r);
    v2 p2 = t[1]+t[5], m2 = t[1]-t[5], q2 = t[3]+t[7], r2 = t[3]-t[7];
    v2 O0 = p2+q2, O2 = p2-q2;
    v2 O1 = pk_subrot(m2, r2), O3 = pk_addrot(m2, r2);
    v2 W1O = RH * pk_subrot(O1, O1);
    v2 A3f = RH * pk_addrot(O3, O3);
    y[0] = E0 + O0;  y[4] = E0 - O0;
    y[1] = E1 + W1O; y[5] = E1 - W1O;
    y[2] = pk_subrot(E2, O2); y[6] = pk_addrot(E2, O2);
    y[3] = E3 - A3f; y[7] = E3 + A3f;
}

// Wave-locality: for Q in {1,8,64}, thread t's butterfly addresses lie in the
// aligned 512-elem region [512*(t>>6), +512), owned exclusively by t's wave.

// ---- radix-8 DIT pass, inverse, in-place over 4096 elems.
template<int Q, bool BAR>
__device__ __forceinline__ void r8_dit_inv(v2* buf, int tid, const v2* twd) {
    int j = tid & (Q-1);
    v2 W[7];
    load_row(twd, (512/Q)*j, W);
    int base = 8*tid - 7*j;
    v2 t[8];
    #pragma unroll
    for (int k = 0; k < 8; ++k) t[k] = buf[SW(base + k*Q)];
    #pragma unroll
    for (int k = 0; k < 7; ++k) t[k+1] = vcmul(t[k+1], W[k]);
    v2 y[8];
    dft8_inv(t, y);
    #pragma unroll
    for (int m = 0; m < 8; ++m) buf[SW(base + m*Q)] = y[m];
    if (BAR) __syncthreads();
    else     __builtin_amdgcn_wave_barrier();
}

// ---- radix-8 DIF pass, forward, applied to BOTH 4096-halves of buf (serial).
template<int Q, bool BAR>
__device__ __forceinline__ void r8_dif_fwd(v2* buf, int tid, const v2* twd) {
    if (Q == 1) {
        const int b0  = tid << 6;
        const int bt  = tid << 3;
        const int mLs = (((bt>>5) ^ (bt>>9)) & 15) << 3;
        const int msU = (mLs ^ 64) + 32768;
        #pragma unroll 1
        for (int hh = 0; hh < 2; ++hh) {
            const int ms = hh ? msU : mLs;
            v2 t[8];
            #pragma unroll
            for (int k = 0; k < 8; ++k)
                t[k] = *(v2*)((char*)buf + ((b0 + (k<<3)) ^ ms));
            v2 y[8];
            dft8_fwd(t, y);
            #pragma unroll
            for (int m = 0; m < 8; ++m)
                *(v2*)((char*)buf + ((b0 + (m<<3)) ^ ms)) = y[m];
        }
        if (BAR) __syncthreads();
        else     __builtin_amdgcn_wave_barrier();
        return;
    }
    int j = tid & (Q-1);
    int baseL = 8*tid - 7*j;
    v2 W[7];
    load_row(twd, (512/Q)*j, W);
    #pragma unroll 1
    for (int hh = 0; hh < 2; ++hh) {
        int base = baseL + (hh << 12);
        v2 t[8];
        #pragma unroll
        for (int k = 0; k < 8; ++k) t[k] = buf[SW(base + k*Q)];
        v2 y[8];
        dft8_fwd(t, y);
        #pragma unroll
        for (int k = 0; k < 7; ++k) y[k+1] = vcmulc(y[k+1], W[k]);
        #pragma unroll
        for (int m = 0; m < 8; ++m) buf[SW(base + m*Q)] = y[m];
    }
    if (BAR) __syncthreads();
    else     __builtin_amdgcn_wave_barrier();
}

// ---- merged prep kernel: blocks 0..H-1 compute per-(h,n) Cauchy weights;
//      the LAST block (blockIdx == H) fills the twiddle table.
//      ws1 layout: 2 floats per (h,n) = (|P|^2, lre^2) -- an even-aligned
//      SGPR pair in the main kernel (broadcast sources for VOP3P).
__global__ void __launch_bounds__(64)
s4_prep(const float* __restrict__ Lre, const float* __restrict__ Lim,
        const float* __restrict__ Pre, const float* __restrict__ Pim,
        const float* __restrict__ Bre, const float* __restrict__ Bim,
        const float* __restrict__ Cin,
        float* __restrict__ ws8, float* __restrict__ ws1,
        v2* __restrict__ twd)
{
    int b = blockIdx.x;
    if (b == (int)gridDim.x - 1) {
        // twiddle block: 64 threads x 8 rows
        const float fm = 6.2831853072f / 4096.0f;
        #pragma unroll
        for (int r = 0; r < 8; ++r) {
            int j = r*64 + (int)threadIdx.x;
            #pragma unroll
            for (int k = 0; k < 7; ++k) {
                float s, c; __sincosf(fm * (float)(j*(k+1)), &s, &c);
                twd[j*8 + k] = (v2){c, s};
            }
            twd[j*8 + 7] = (v2){1.0f, 0.0f};
        }
        return;
    }
    int idx = b*64 + threadIdx.x;   // h*64 + n
    float lre = fminf(Lre[idx], -1e-4f);
    float lim = Lim[idx];
    float pr = Pre[idx], pi = Pim[idx];
    float br = Bre[idx], bi = Bim[idx];
    float cr = Cin[2*idx], ci = Cin[2*idx+1];
    v2 cc = (v2){cr, -ci};
    v2 w00 = vcmul(cc, (v2){br, bi});
    v2 w01 = vcmul(cc, (v2){pr, pi});
    v2 w10 = vcmul((v2){pr,-pi}, (v2){br, bi});
    float* o = ws8 + idx*8;
    o[0] = -lre;  o[1] = -lim;
    o[2] = w00.x; o[3] = w00.y;
    o[4] = w01.x; o[5] = w01.y;
    o[6] = w10.x; o[7] = w10.y;
    ws1[2*idx]   = pr*pr + pi*pi;
    ws1[2*idx+1] = lre*lre;
}

// Fused S4 layer, one block per channel h. R7 structure (79.1 us fused) --
// the R8 kernel-split regressed (occupancy is not the lever: VALUBusy flat
// at 8 waves/SIMD) and is reverted. This round adds only the P5 asm
// micro-packing: a+/-conj(b), 0.5*t, -0.5*i*t each as ONE modifier-folded
// v_pk op (was 3-4 compiler-lowered ops each).
__global__ __attribute__((amdgpu_waves_per_eu(4, 4))) void __launch_bounds__(NT)
s4_fused(const float* __restrict__ u,
         const float* __restrict__ Din, const float* __restrict__ logstep,
         const float* __restrict__ ws8, const float* __restrict__ ws1,
         const v2* __restrict__ twd,
         float* __restrict__ out)
{
    __shared__ v2 buf[8192];   // 64 KB -> 2 blocks/CU
    const int tid = threadIdx.x;
    const int h = blockIdx.x;
    const int tbs = (tid ^ ((tid>>5) & 15)) << 3;

    const float step = expf(logstep[h]);
    const float tos  = 2.0f / step;
    const float hstep = 0.5f * step;
    const float* pp = ws8 + (h*64)*8;
    const float4* pp4 = (const float4*)pp;
    const v2* pw2 = (const v2*)(ws1 + h*128);

    // ---- P1: Cauchy kernel; hp0's 4 results staged raw in LDS, hp1's kept in
    //      regs; then the P2 Q=1 butterfly runs in registers. ----
    v2 a4[4];
    #pragma unroll 1
    for (int hp = 0; hp < 2; ++hp) {
        v2 tvA, tvB;
        {
            float tv[4];
            #pragma unroll
            for (int i = 0; i < 4; ++i) {
                int l = hp*(4*NT) + i*NT + tid;
                float ang = -6.2831855f * ((float)l * (1.0f/4096.0f));
                float sh, ch; __sincosf(0.5f*ang, &sh, &ch);
                float traw = -tos * sh * __builtin_amdgcn_rcpf(ch);
                tv[i] = fminf(fmaxf(traw, -1e12f), 1e12f);
            }
            tvA = (v2){tv[0], tv[1]};
            tvB = (v2){tv[2], tv[3]};
        }
        v2 aX00A=(v2)(0.f), aY00A=(v2)(0.f), aX00B=(v2)(0.f), aY00B=(v2)(0.f);
        v2 aX01A=(v2)(0.f), aY01A=(v2)(0.f), aX01B=(v2)(0.f), aY01B=(v2)(0.f);
        v2 aX10A=(v2)(0.f), aY10A=(v2)(0.f), aX10B=(v2)(0.f), aY10B=(v2)(0.f);
        v2 aX11A=(v2)(0.f), aY11A=(v2)(0.f), aX11B=(v2)(0.f), aY11B=(v2)(0.f);
        #pragma unroll 2
        for (int n = 0; n < 64; ++n) {
            float4 A = pp4[2*n], Bq = pp4[2*n+1];
            v2 lam = (v2){A.x, A.y};
            v2 w00 = (v2){A.z, A.w};
            v2 w01 = (v2){Bq.x, Bq.y};
            v2 w10 = (v2){Bq.z, Bq.w};
            v2 Wv  = pw2[n];
            v2 sA = pk_add_bh(tvA, lam), sB = pk_add_bh(tvB, lam);
            v2 dA = pk_fma_sq_bh(sA, Wv), dB = pk_fma_sq_bh(sB, Wv);
            v2 PA = pk_mul_cross(dA), PB = pk_mul_cross(dB);
            v2 RR;
            RR.x = __builtin_amdgcn_rcpf(PA.x);
            RR.y = __builtin_amdgcn_rcpf(PB.x);
            v2 invA = pk_inv_lo(RR, dA), invB = pk_inv_hi(RR, dB);
            v2 pxA = pk_mul_bl(invA, lam), pxB = pk_mul_bl(invB, lam);
            v2 pyA = pk_mulp(invA, sA),    pyB = pk_mulp(invB, sB);
            fmaBlo(aX00A, w00, pxA); fmaBhi(aX00A, w00, pyA);
            fmaBhi(aY00A, w00, pxA); fmaBlon(aY00A, w00, pyA);
            fmaBlo(aX00B, w00, pxB); fmaBhi(aX00B, w00, pyB);
            fmaBhi(aY00B, w00, pxB); fmaBlon(aY00B, w00, pyB);
            fmaBlo(aX01A, w01, pxA); fmaBhi(aX01A, w01, pyA);
            fmaBhi(aY01A, w01, pxA); fmaBlon(aY01A, w01, pyA);
            fmaBlo(aX01B, w01, pxB); fmaBhi(aX01B, w01, pyB);
            fmaBhi(aY01B, w01, pxB); fmaBlon(aY01B, w01, pyB);
            fmaBlo(aX10A, w10, pxA); fmaBhi(aX10A, w10, pyA);
            fmaBhi(aY10A, w10, pxA); fmaBlon(aY10A, w10, pyA);
            fmaBlo(aX10B, w10, pxB); fmaBhi(aX10B, w10, pyB);
            fmaBhi(aY10B, w10, pxB); fmaBlon(aY10B, w10, pyB);
            fmaBlo(aX11A, Wv, pxA);  fmaBlon(aY11A, Wv, pyA);
            fmaBlo(aX11B, Wv, pxB);  fmaBlon(aY11B, Wv, pyB);
        }
        float tvv[4] = { tvA.x, tvA.y, tvB.x, tvB.y };
        v2 k00[4] = { {aX00A.x,aY00A.x}, {aX00A.y,aY00A.y},
                      {aX00B.x,aY00B.x}, {aX00B.y,aY00B.y} };
        v2 k01[4] = { {aX01A.x,aY01A.x}, {aX01A.y,aY01A.y},
                      {aX01B.x,aY01B.x}, {aX01B.y,aY01B.y} };
        v2 k10[4] = { {aX10A.x,aY10A.x}, {aX10A.y,aY10A.y},
                      {aX10B.x,aY10B.x}, {aX10B.y,aY10B.y} };
        v2 k11[4] = { {aX11A.x,aY11A.x}, {aX11A.y,aY11A.y},
                      {aX11B.x,aY11B.x}, {aX11B.y,aY11B.y} };
        #pragma unroll
        for (int i = 0; i < 4; ++i) {
            v2 opk = (v2){1.0f + k11[i].x, k11[i].y};
            float iv = __builtin_amdgcn_rcpf(opk.x*opk.x + opk.y*opk.y);
            v2 r11 = vconj(opk) * iv;
            v2 t  = vcmul(vcmul(k01[i], r11), k10[i]);
            v2 cf = (v2){1.0f, tvv[i]*hstep};
            v2 res = vcmul(cf, k00[i] - t);
            if (hp == 0) q512(buf, tbs, i) = res;
            else         a4[i] = res;
        }
    }
    {   // fused P2 Q=1 butterfly: t[k] = atRoots[tid + 512k]
        v2 t[8];
        #pragma unroll
        for (int k = 0; k < 4; ++k) t[k] = q512(buf, tbs, k);
        #pragma unroll
        for (int k = 0; k < 4; ++k) t[4+k] = a4[k];
        __syncthreads();
        v2 y[8];
        dft8_inv(t, y);
        const int tb8 = 8*rev3(tid);
        const int b8  = tb8 << 3;
        const int m8s = (((tb8>>5) ^ (tb8>>9)) & 15) << 3;
        #pragma unroll
        for (int m = 0; m < 8; ++m)
            *(v2*)((char*)buf + ((b8 + (m<<3)) ^ m8s)) = y[m];
    }
    __syncthreads();

    // ---- P2: ifft4096 middle passes ----
    r8_dit_inv<8,  false>(buf, tid, twd);
    r8_dit_inv<64, true >(buf, tid, twd);

    // ---- P3: fused P2-Q512 (DIT) + pack z = u + i*K + r2 stage + DIF-Q512. ----
    {
        v2 W[7];
        load_row(twd, tid, W);
        v2 t[8];
        #pragma unroll
        for (int k = 0; k < 8; ++k) t[k] = q512(buf, tbs, k);
        #pragma unroll
        for (int k = 0; k < 7; ++k) t[k+1] = vcmul(t[k+1], W[k]);
        v2 y[8];
        dft8_inv(t, y);
        float uval[8];
        const float* up = u + h*4096;
        #pragma unroll
        for (int m = 0; m < 8; ++m) uval[m] = up[tid + 512*m];
        float s2, c2; __sincosf(-6.2831853072f/8192.0f*(float)tid, &s2, &c2);
        v2 cur0 = (v2){c2, s2};
        const v2 C16n = (v2){0.92387953f, -0.38268343f};
        v2 zL[8], zU[8];
        {
            v2 cur = cur0;
            #pragma unroll
            for (int k = 0; k < 8; ++k) {
                zL[k] = (v2){uval[k], y[k].x * (1.0f/4096.0f)};
                zU[k] = vcmul(zL[k], cur);
                cur = vcmul(cur, C16n);
            }
        }
        v2 s[8];
        dft8_fwd(zL, s);
        #pragma unroll
        for (int m = 1; m < 8; ++m) s[m] = vcmulc(s[m], W[m-1]);
        #pragma unroll
        for (int m = 0; m < 8; ++m) q512(buf, tbs, m) = s[m];
        dft8_fwd(zU, s);
        #pragma unroll
        for (int m = 1; m < 8; ++m) s[m] = vcmulc(s[m], W[m-1]);
        #pragma unroll
        for (int m = 0; m < 8; ++m) q512u(buf, tbs, m) = s[m];
    }
    __syncthreads();

    // ---- P4: forward fft8192 remaining stages ----
    r8_dif_fwd<64, false>(buf, tid, twd);
    r8_dif_fwd<8,  false>(buf, tid, twd);
    r8_dif_fwd<1,  true >(buf, tid, twd);

    // ---- P5: unpack + multiply + half-size-inverse pack, fused with P6 Q=1
    //      butterfly. U/K extraction in modifier-folded v_pk ops. ----
    {
        float sb, cb; __sincosf(6.2831853072f/8192.0f*(float)tid, &sb, &cb);
        v2 cur = (v2){cb, sb};
        const v2 C16p = (v2){0.92387953f, 0.38268343f};
        v2 v[8];
        #pragma unroll 1
        for (int i = 0; i < 8; ++i) {
            int r  = i*NT + tid;
            int par = (r&1)<<12;
            int e1 = par + d8r4(r>>1);
            int e3 = e1 + 4;
            int k2c = 4096 - r;
            int e4 = ((k2c&1)<<12) + d8r4((k2c>>1)&4095);
            int e2 = (r == 0) ? 0 : (e4 + 4);
            v2 za = buf[SW(e1)];
            v2 zb = buf[SW(e2)];
            v2 zc = buf[SW(e3)];
            v2 zd = buf[SW(e4)];
            v2 U1 = pk_half(pk_addc(za, zb));            // 0.5*(za + conj zb)
            v2 K1 = pk_nih (pk_subc(za, zb));            // -0.5*i*(za - conj zb)
            v2 Yr = vcmul(U1, K1);
            v2 U2 = pk_half(pk_addc(zc, zd));
            v2 K2 = pk_nih (pk_subc(zc, zd));
            v2 Ys = vcmul(U2, K2);
            v[i] = pk_addrot(Yr + Ys, vcmul(cur, Yr - Ys));
            cur = vcmul(cur, C16p);
        }
        __syncthreads();
        v2 y[8];
        dft8_inv(v, y);
        const int tb8 = 8*rev3(tid);
        const int b8  = tb8 << 3;
        const int m8s = (((tb8>>5) ^ (tb8>>9)) & 15) << 3;
        #pragma unroll
        for (int m = 0; m < 8; ++m)
            *(v2*)((char*)buf + ((b8 + (m<<3)) ^ m8s)) = y[m];
    }
    __syncthreads();

    // ---- P6: ifft4096 middle passes ----
    r8_dit_inv<8,  false>(buf, tid, twd);
    r8_dit_inv<64, true >(buf, tid, twd);

    // ---- P7: fused P6-Q512 butterfly + epilogue. ----
    {
        v2 W[7];
        load_row(twd, tid, W);
        v2 t[8];
        #pragma unroll
        for (int k = 0; k < 8; ++k) t[k] = q512(buf, tbs, k);
        #pragma unroll
        for (int k = 0; k < 7; ++k) t[k+1] = vcmul(t[k+1], W[k]);
        v2 y[4];
        dft8_inv_lo4(t, y);
        const float Dh = Din[h];
        const float sc = 1.0f / 8192.0f;
        const v2* u2 = (const v2*)(u + h*4096);
        v2*     out2 = (v2*)(out + h*4096);
        #pragma unroll
        for (int m = 0; m < 4; ++m) {
            int n = tid + 512*m;
            out2[n] = sc*y[m] + Dh*u2[n];
        }
    }
}

extern "C" void kernel_launch(void* const* d_in, const int* in_sizes, int n_in,
                              void* d_out, int out_size, void* d_ws, size_t ws_size,
                              hipStream_t stream)
{
    const float* u       = (const float*)d_in[0];
    const float* Lre     = (const float*)d_in[1];
    const float* Lim     = (const float*)d_in[2];
    const float* Pre     = (const float*)d_in[3];
    const float* Pim     = (const float*)d_in[4];
    const float* Bre     = (const float*)d_in[5];
    const float* Bim     = (const float*)d_in[6];
    const float* Cin     = (const float*)d_in[7];
    const float* Din     = (const float*)d_in[8];
    const float* logstep = (const float*)d_in[9];
    float* out = (float*)d_out;
    const int H = in_sizes[8];  // D is [H,1]

    float* ws8 = (float*)d_ws;            // H*64*8 floats (1 MB)
    float* ws1 = ws8 + (size_t)H*64*8;    // H*128 floats (256 KB): (|P|^2, lre^2)
    v2*    twd = (v2*)(ws1 + (size_t)H*128);  // 512 rows x 8 v2 (32 KB)

    hipLaunchKernelGGL(s4_prep, dim3(H + 1), dim3(64), 0, stream,
                       Lre, Lim, Pre, Pim, Bre, Bim, Cin, ws8, ws1, twd);
    hipLaunchKernelGGL(s4_fused, dim3(H), dim3(NT), 0, stream,
                       u, Din, logstep, ws8, ws1, twd, out);
}